// Round 10
// baseline (831.524 us; speedup 1.0000x reference)
//
#include <hip/hip_runtime.h>
#include <cstddef>

// EfficientAttention pipeline, MI355X. fp32 throughout.
// B=64, DIM=128, N=4000, H=4, DH=32, CL=50, K=9.
// R12: k_e1ucx + k_e2 merged into one role-interleaved kernel (bid%5<2 -> e1,
// else e2; 1280 blocks). Both are independent (read x+stats only); union LDS
// 76KB -> still 2 blk/CU, so e2-role blocks co-resident with e1-role blocks
// fill e1's 39% barrier-idle cycles. Bodies verbatim from R11 (verified).

// ---- workspace offsets (in floats) ----
constexpr size_t O_MU    = 0;                   // 8192
constexpr size_t O_RINV  = 8192;
constexpr size_t O_RATIO = 16384;
constexpr size_t O_A1    = 24576;
constexpr size_t O_B1    = 24704;
constexpr size_t O_A2    = 24832;
constexpr size_t O_B2    = 24960;
constexpr size_t O_PROJWT= 25088;               // 128x128 proj_w^T [d][o]
constexpr size_t O_VPROJ = 41472;               // 128
constexpr size_t O_MT    = 41600;               // 256x128 -> end 74368
constexpr size_t O_E2    = 74368;               // 64*50*4000 exp(embed2)
constexpr size_t O_UCXP  = 12874368;            // 8*64*132*56 = 3784704
constexpr size_t O_XT    = 16659072;            // 4x 409600
constexpr size_t O_QT    = 17068672;
constexpr size_t O_KT    = 17478272;
constexpr size_t O_VT    = 17887872;
constexpr size_t O_H1    = 18297472;            // 1228800
constexpr size_t O_P1    = 19526272;            // 16384
constexpr size_t O_H2    = 19542656;            // 409600
constexpr size_t O_P2    = 19952256;            // 16384
constexpr size_t O_CAT   = 19968640;            // 819200
constexpr size_t O_PRES2 = 20787840;            // 409600 -> 21197440 (84.8MB peak)

// ---------------- K1: instance-norm stats (wave-per-row) + PROJWT transpose ----------------
__global__ __launch_bounds__(256) void k_stats(const float* __restrict__ x,
                                               const float* __restrict__ projw,
                                               float* __restrict__ ws){
  if(blockIdx.x >= 2048){
    int i = (blockIdx.x - 2048)*256 + threadIdx.x;
    int o = i & 127, k = i >> 7;
    ws[O_PROJWT + i] = projw[o*128 + k];
    return;
  }
  int w = threadIdx.x >> 6, lane = threadIdx.x & 63;
  int row = blockIdx.x*4 + w;
  const float4* xr = (const float4*)(x + (size_t)row * 4000);
  float s = 0.f, sq = 0.f;
  for(int i = lane; i < 1000; i += 64){
    float4 v = xr[i];
    s  += v.x + v.y + v.z + v.w;
    sq += v.x*v.x + v.y*v.y + v.z*v.z + v.w*v.w;
  }
  for(int off = 32; off > 0; off >>= 1){
    s  += __shfl_down(s,  off, 64);
    sq += __shfl_down(sq, off, 64);
  }
  if(lane == 0){
    float mean = s * (1.f/4000.f);
    float var  = sq * (1.f/4000.f) - mean*mean;
    ws[O_MU   + row] = mean;
    ws[O_RINV + row] = rsqrtf(var + 1e-3f);
    ws[O_RATIO+ row] = var / (var + 1e-3f);
  }
}

// ---------------- K2: M^T (0..127), VPROJ (128), BN affine prep (129) ----------------
__global__ __launch_bounds__(256) void k_mprep(const float* __restrict__ presw,
                                               const float* __restrict__ presb,
                                               const float* __restrict__ g1g,
                                               const float* __restrict__ g1b,
                                               const float* __restrict__ g2g,
                                               const float* __restrict__ g2b,
                                               float* __restrict__ ws){
  int t = threadIdx.x;
  if(blockIdx.x < 128){
    int kk2 = blockIdx.x * 2;
    __shared__ float pwc[2][128];
    { int which = t >> 7, d = t & 127; pwc[which][d] = presw[d*256 + kk2 + which]; }
    __syncthreads();
    int which = t >> 7, o = t & 127;
    float acc = 0.f;
    for(int d = 0; d < 128; d++) acc += ws[O_PROJWT + d*128 + o] * pwc[which][d];
    ws[O_MT + (size_t)(kk2 + which)*128 + o] = acc;
  }else if(blockIdx.x == 128){
    if(t < 128){
      float v = 0.f;
      for(int d = 0; d < 128; d++) v += ws[O_PROJWT + d*128 + t] * presb[d];
      ws[O_VPROJ + t] = v;
    }
  }else{
    if(t < 128){
      float s = 0.f;
      for(int b = 0; b < 64; b++) s += ws[O_RATIO + b*128 + t];
      float var2 = s * (1.f/64.f);
      float inv2 = rsqrtf(var2 + 1e-5f);
      ws[O_A1+t] = g1g[t] * inv2;  ws[O_B1+t] = g1b[t];
      ws[O_A2+t] = g2g[t] * inv2;  ws[O_B2+t] = g2b[t];
    }
  }
}

// ---------------- K3: merged embed kernel ----------------
// Role by bid%5: {0,1} -> e1ucx (512 blocks, ch 0..7, chunk 500, 76KB path),
// {2,3,4} -> e2 (768 blocks, ch 0..11, chunk 336, 51KB path). Union LDS 19448
// floats (77792B) -> 2 blk/CU; e2 blocks overlap e1 barrier stalls.
__global__ __launch_bounds__(256) void k_embed(const float* __restrict__ x,
    const float* __restrict__ wg1, const float* __restrict__ bg1,
    const float* __restrict__ wg2, const float* __restrict__ bg2,
    float* __restrict__ ws){
  __shared__ float smem[19448];
  int bid = blockIdx.x;
  int grp = bid / 5, role = bid % 5;
  int t = threadIdx.x;

  if(role < 2){
    // ================= e1ucx body =================
    int idx = grp*2 + role;
    int ch = idx & 7, b = idx >> 3;
    float* lW1  = smem;            // 6656
    float* lrv1 = smem + 6656;     // 6144
    float* lxt  = smem + 12800;    // 6336
    float* ca1  = smem + 19136;    // 128
    float* cb1  = smem + 19264;    // 128
    float* bg1p = smem + 19392;    // 56
    if(t < 128){
      float mu = ws[O_MU + b*128 + t], ri = ws[O_RINV + b*128 + t];
      float a1 = ws[O_A1+t]*ri;
      ca1[t] = a1; cb1[t] = ws[O_B1+t] - a1*mu;
    }
    if(t >= 128 && t < 184){ int q = t - 128; bg1p[q] = (q < 50) ? bg1[q] : 0.f; }
    for(int i = t; i < 1664; i += 256){
      int cl = i >> 5, cq = i & 31;
      float4 w = (cl < 50) ? *(const float4*)&wg1[cl*128 + cq*4] : make_float4(0.f,0.f,0.f,0.f);
      int c0 = cq*4;
      lW1[(c0+0)*52+cl] = w.x; lW1[(c0+1)*52+cl] = w.y;
      lW1[(c0+2)*52+cl] = w.z; lW1[(c0+3)*52+cl] = w.w;
    }
    int dg = t & 31, cg = t >> 5;
    float ua[4][8];
    #pragma unroll
    for(int r = 0; r < 4; r++)
      #pragma unroll
      for(int i = 0; i < 8; i++) ua[r][i] = 0.f;
    float zacc = 0.f;
    int ig = t >> 4, jg = t & 15;
    int clb = ig*4, j4 = jg*4;
    int sc[6], sj[6];
    float4 pf[6];
    #pragma unroll
    for(int j = 0; j < 6; j++){ int i = t + 256*j; sc[j] = i/12; sj[j] = (i%12)*4; }
    #pragma unroll
    for(int j = 0; j < 6; j++)
      pf[j] = *(const float4*)&x[(size_t)(b*128 + sc[j])*4000 + ch*500 + sj[j]];

    for(int st = 0; st < 11; st++){
      int lim = (st == 10) ? 20 : 48;
      __syncthreads();
      #pragma unroll
      for(int j = 0; j < 6; j++){
        int c = sc[j], jj = sj[j];
        float4 xv = (jj < lim) ? pf[j] : make_float4(0.f,0.f,0.f,0.f);
        lxt[(jj+0)*132 + c] = xv.x; lxt[(jj+1)*132 + c] = xv.y;
        lxt[(jj+2)*132 + c] = xv.z; lxt[(jj+3)*132 + c] = xv.w;
        float a1 = ca1[c], b1v = cb1[c];
        float4 r1;
        r1.x = fmaxf(a1*xv.x + b1v, 0.f); r1.y = fmaxf(a1*xv.y + b1v, 0.f);
        r1.z = fmaxf(a1*xv.z + b1v, 0.f); r1.w = fmaxf(a1*xv.w + b1v, 0.f);
        *(float4*)&lrv1[c*48 + jj] = r1;
      }
      __syncthreads();
      if(st < 10){
        int lim2 = (st == 9) ? 20 : 48;
        int nb2 = ch*500 + (st+1)*48;
        #pragma unroll
        for(int j = 0; j < 6; j++)
          pf[j] = (sj[j] < lim2) ? *(const float4*)&x[(size_t)(b*128 + sc[j])*4000 + nb2 + sj[j]]
                                 : make_float4(0.f,0.f,0.f,0.f);
      }
      float e[4][4];
      if(ig < 13 && jg < 12){
        #pragma unroll
        for(int r = 0; r < 4; r++){ e[r][0]=0.f; e[r][1]=0.f; e[r][2]=0.f; e[r][3]=0.f; }
        #pragma unroll 4
        for(int c = 0; c < 128; c++){
          float4 w = *(const float4*)&lW1[c*52 + clb];
          float4 v = *(const float4*)&lrv1[c*48 + j4];
          e[0][0] += w.x*v.x; e[0][1] += w.x*v.y; e[0][2] += w.x*v.z; e[0][3] += w.x*v.w;
          e[1][0] += w.y*v.x; e[1][1] += w.y*v.y; e[1][2] += w.y*v.z; e[1][3] += w.y*v.w;
          e[2][0] += w.z*v.x; e[2][1] += w.z*v.y; e[2][2] += w.z*v.z; e[2][3] += w.z*v.w;
          e[3][0] += w.w*v.x; e[3][1] += w.w*v.y; e[3][2] += w.w*v.z; e[3][3] += w.w*v.w;
        }
      }
      __syncthreads();               // E1 reads of lrv1 done -> overlay eU
      if(ig < 13 && jg < 12){
        bool live = (j4 < lim);
        #pragma unroll
        for(int r = 0; r < 4; r++){
          float bias = bg1p[clb + r];
          float4 u = make_float4(0.f,0.f,0.f,0.f);
          if(live){
            u.x = expf(e[r][0] + bias); u.y = expf(e[r][1] + bias);
            u.z = expf(e[r][2] + bias); u.w = expf(e[r][3] + bias);
          }
          *(float4*)&lrv1[(clb + r)*48 + j4] = u;
        }
      }
      __syncthreads();
      if(t < 224){
        int d4 = dg*4, c8 = cg*8;
        for(int n4 = 0; n4 < 12; n4++){
          int n0 = n4*4;
          float4 uv[8];
          #pragma unroll
          for(int i = 0; i < 8; i++) uv[i] = *(const float4*)&lrv1[(c8 + i)*48 + n0];
          {
            float4 xq = *(const float4*)&lxt[(n0+0)*132 + d4];
            #pragma unroll
            for(int i = 0; i < 8; i++){
              float u = uv[i].x;
              ua[0][i] += xq.x*u; ua[1][i] += xq.y*u; ua[2][i] += xq.z*u; ua[3][i] += xq.w*u;
            }
          }
          {
            float4 xq = *(const float4*)&lxt[(n0+1)*132 + d4];
            #pragma unroll
            for(int i = 0; i < 8; i++){
              float u = uv[i].y;
              ua[0][i] += xq.x*u; ua[1][i] += xq.y*u; ua[2][i] += xq.z*u; ua[3][i] += xq.w*u;
            }
          }
          {
            float4 xq = *(const float4*)&lxt[(n0+2)*132 + d4];
            #pragma unroll
            for(int i = 0; i < 8; i++){
              float u = uv[i].z;
              ua[0][i] += xq.x*u; ua[1][i] += xq.y*u; ua[2][i] += xq.z*u; ua[3][i] += xq.w*u;
            }
          }
          {
            float4 xq = *(const float4*)&lxt[(n0+3)*132 + d4];
            #pragma unroll
            for(int i = 0; i < 8; i++){
              float u = uv[i].w;
              ua[0][i] += xq.x*u; ua[1][i] += xq.y*u; ua[2][i] += xq.z*u; ua[3][i] += xq.w*u;
            }
          }
        }
      }
      if(t < 52){
        float s = 0.f;
        #pragma unroll
        for(int k = 0; k < 12; k++){
          float4 u = *(const float4*)&lrv1[t*48 + k*4];
          s += u.x + u.y + u.z + u.w;
        }
        zacc += s;
      }
    }
    if(t < 224){
      int d4 = dg*4, c8 = cg*8;
      #pragma unroll
      for(int r = 0; r < 4; r++){
        size_t base = O_UCXP + ((size_t)(ch*64 + b)*132 + d4 + r)*56 + c8;
        *(float4*)&ws[base]     = make_float4(ua[r][0], ua[r][1], ua[r][2], ua[r][3]);
        *(float4*)&ws[base + 4] = make_float4(ua[r][4], ua[r][5], ua[r][6], ua[r][7]);
      }
    }
    if(t < 52) ws[O_UCXP + ((size_t)(ch*64 + b)*132 + 128)*56 + t] = zacc;
  }else{
    // ================= e2 body =================
    int idx = grp*3 + (role - 2);
    int ch = idx % 12, b = idx / 12;
    float* lW2  = smem;            // 6656
    float* lrv2 = smem + 6656;     // 6144
    float* ca2  = smem + 12800;    // 128
    float* cb2  = smem + 12928;    // 128
    float* bg2p = smem + 13056;    // 56
    if(t < 128){
      float mu = ws[O_MU + b*128 + t], ri = ws[O_RINV + b*128 + t];
      float a2 = ws[O_A2+t]*ri;
      ca2[t] = a2; cb2[t] = ws[O_B2+t] - a2*mu;
    }
    if(t >= 192 && t < 248){ int q = t - 192; bg2p[q] = (q < 50) ? bg2[q] : 0.f; }
    for(int i = t; i < 1664; i += 256){
      int cl = i >> 5, cq = i & 31;
      float4 w = (cl < 50) ? *(const float4*)&wg2[cl*128 + cq*4] : make_float4(0.f,0.f,0.f,0.f);
      int c0 = cq*4;
      lW2[(c0+0)*52+cl] = w.x; lW2[(c0+1)*52+cl] = w.y;
      lW2[(c0+2)*52+cl] = w.z; lW2[(c0+3)*52+cl] = w.w;
    }
    int ig = t >> 4, jg = t & 15;
    int clb = ig*4, j4 = jg*4;
    int sc[6], sj[6];
    float4 pf[6];
    #pragma unroll
    for(int j = 0; j < 6; j++){ int i = t + 256*j; sc[j] = i/12; sj[j] = (i%12)*4; }
    #pragma unroll
    for(int j = 0; j < 6; j++)
      pf[j] = *(const float4*)&x[(size_t)(b*128 + sc[j])*4000 + ch*336 + sj[j]];

    for(int st = 0; st < 7; st++){
      int nb = ch*336 + st*48;
      int lim = 4000 - nb; if(lim > 48) lim = 48;
      __syncthreads();
      #pragma unroll
      for(int j = 0; j < 6; j++){
        int c = sc[j], jj = sj[j];
        float4 xv = (jj < lim) ? pf[j] : make_float4(0.f,0.f,0.f,0.f);
        float a2 = ca2[c], b2v = cb2[c];
        float4 r2;
        r2.x = fmaxf(a2*xv.x + b2v, 0.f); r2.y = fmaxf(a2*xv.y + b2v, 0.f);
        r2.z = fmaxf(a2*xv.z + b2v, 0.f); r2.w = fmaxf(a2*xv.w + b2v, 0.f);
        *(float4*)&lrv2[c*48 + jj] = r2;
      }
      __syncthreads();
      if(st < 6){
        int nb2 = nb + 48;
        int lim2 = 4000 - nb2; if(lim2 > 48) lim2 = 48;
        #pragma unroll
        for(int j = 0; j < 6; j++)
          pf[j] = (sj[j] < lim2) ? *(const float4*)&x[(size_t)(b*128 + sc[j])*4000 + nb2 + sj[j]]
                                 : make_float4(0.f,0.f,0.f,0.f);
      }
      if(ig < 13 && jg < 12){
        float e[4][4];
        #pragma unroll
        for(int r = 0; r < 4; r++){ e[r][0]=0.f; e[r][1]=0.f; e[r][2]=0.f; e[r][3]=0.f; }
        #pragma unroll 4
        for(int c = 0; c < 128; c++){
          float4 w = *(const float4*)&lW2[c*52 + clb];
          float4 v = *(const float4*)&lrv2[c*48 + j4];
          e[0][0] += w.x*v.x; e[0][1] += w.x*v.y; e[0][2] += w.x*v.z; e[0][3] += w.x*v.w;
          e[1][0] += w.y*v.x; e[1][1] += w.y*v.y; e[1][2] += w.y*v.z; e[1][3] += w.y*v.w;
          e[2][0] += w.z*v.x; e[2][1] += w.z*v.y; e[2][2] += w.z*v.z; e[2][3] += w.z*v.w;
          e[3][0] += w.w*v.x; e[3][1] += w.w*v.y; e[3][2] += w.w*v.z; e[3][3] += w.w*v.w;
        }
        if(j4 < lim){
          #pragma unroll
          for(int r = 0; r < 4; r++){
            int cl = clb + r;
            if(cl < 50){
              float bias = bg2p[cl];
              float4 o = make_float4(expf(e[r][0]+bias), expf(e[r][1]+bias),
                                     expf(e[r][2]+bias), expf(e[r][3]+bias));
              *(float4*)&ws[O_E2 + ((size_t)b*50 + cl)*4000 + nb + j4] = o;
            }
          }
        }
      }
    }
  }
}

// ---------------- K5: qkv + qkv1 projections, cluster_x reduced on load (8 chunks) ----------------
__global__ __launch_bounds__(256) void k_qkv(const float* __restrict__ qw,
                                             const float* __restrict__ qb,
                                             const float* __restrict__ q1w,
                                             const float* __restrict__ q1b,
                                             float* __restrict__ ws){
  int rt = blockIdx.x, b = blockIdx.y;        // 8 row-tiles of 64
  __shared__ float wl[64*130];                // [rl][k] pad 130
  __shared__ float cxl[128*52];               // [k][c]
  __shared__ float zi[52];
  int t = threadIdx.x;
  if(t < 52){
    float s = 0.f;
    if(t < 50){
      #pragma unroll
      for(int ch = 0; ch < 8; ch++)
        s += ws[O_UCXP + ((size_t)(ch*64 + b)*132 + 128)*56 + t];
      zi[t] = 1.f / s;
    }else zi[t] = 0.f;
  }
  for(int i = t; i < 2048; i += 256){
    int rl = i >> 5, kq = i & 31, row = rt*64 + rl;
    float4 w = (row < 128) ? *(const float4*)&qw[row*128 + kq*4]
                           : *(const float4*)&q1w[(row-128)*128 + kq*4];
    int k0 = kq*4;
    wl[rl*130 + k0+0] = w.x; wl[rl*130 + k0+1] = w.y;
    wl[rl*130 + k0+2] = w.z; wl[rl*130 + k0+3] = w.w;
  }
  __syncthreads();
  for(int i = t; i < 6656; i += 256){
    int k = i / 52, c = i % 52;
    float s = 0.f;
    size_t base = O_UCXP + ((size_t)b*132 + k)*56 + c;
    #pragma unroll
    for(int ch = 0; ch < 8; ch++) s += ws[base + (size_t)ch*473088];
    cxl[i] = s * zi[c];
  }
  __syncthreads();
  int ig = t & 15, cg = t >> 4;
  float acc[4][4];
  #pragma unroll
  for(int r = 0; r < 4; r++){ acc[r][0]=0.f; acc[r][1]=0.f; acc[r][2]=0.f; acc[r][3]=0.f; }
  if(cg < 13){
    int rb = ig*4, cb = cg*4;
    #pragma unroll 4
    for(int k = 0; k < 128; k++){
      float4 cv = *(const float4*)&cxl[k*52 + cb];
      float w0 = wl[(rb+0)*130 + k], w1 = wl[(rb+1)*130 + k];
      float w2 = wl[(rb+2)*130 + k], w3 = wl[(rb+3)*130 + k];
      acc[0][0] += w0*cv.x; acc[0][1] += w0*cv.y; acc[0][2] += w0*cv.z; acc[0][3] += w0*cv.w;
      acc[1][0] += w1*cv.x; acc[1][1] += w1*cv.y; acc[1][2] += w1*cv.z; acc[1][3] += w1*cv.w;
      acc[2][0] += w2*cv.x; acc[2][1] += w2*cv.y; acc[2][2] += w2*cv.z; acc[2][3] += w2*cv.w;
      acc[3][0] += w3*cv.x; acc[3][1] += w3*cv.y; acc[3][2] += w3*cv.z; acc[3][3] += w3*cv.w;
    }
    #pragma unroll
    for(int r = 0; r < 4; r++){
      int row = rt*64 + ig*4 + r;
      size_t base; float bias;
      if(row < 128){
        int h = row >> 5;
        bias = qb[row];
        base = O_XT + (size_t)(b*4 + h)*1600 + (row & 31);
      }else{
        int r2 = row - 128, h = r2/96, j = r2%96, kind = j >> 5, dd = j & 31;
        bias = q1b[r2];
        base = (kind==0 ? O_QT : kind==1 ? O_KT : O_VT) + (size_t)(b*4 + h)*1600 + dd;
      }
      #pragma unroll
      for(int s = 0; s < 4; s++){
        int c = cg*4 + s;
        if(c < 50) ws[base + (size_t)c*32] = acc[r][s] + bias;
      }
    }
  }
}

// ---------------- K6: knn (top-9) + edge + conv1 + BN1 partials ----------------
__global__ __launch_bounds__(256) void k_knn(const float* __restrict__ g1w,
                                             const float* __restrict__ g1bias,
                                             float* __restrict__ ws){
  int h = blockIdx.x, b = blockIdx.y;
  __shared__ float xtl[50][33];
  __shared__ float pdl[50][52];
  __shared__ float sql[50];
  __shared__ int   idxl[50][9];
  __shared__ float w1l[6144];                 // weights; reused as h1 stash for BN1
  int t = threadIdx.x;
  const float* xtg = ws + O_XT + (size_t)(b*4 + h)*1600;
  for(int i = t; i < 1600; i += 256) xtl[i >> 5][i & 31] = xtg[i];
  for(int i = t; i < 6144; i += 256){
    int o = i / 192, r = i % 192, ii = r / 3, tt = r % 3;
    w1l[(ii*3 + tt)*32 + o] = g1w[(size_t)h*6144 + i];
  }
  __syncthreads();
  if(t < 50){
    float s = 0.f;
    for(int d = 0; d < 32; d++){ float v = xtl[t][d]; s += v*v; }
    sql[t] = s;
  }
  __syncthreads();
  for(int i = t; i < 2500; i += 256){
    int n = i / 50, m = i % 50;
    float s = 0.f;
    for(int d = 0; d < 32; d++) s += xtl[n][d]*xtl[m][d];
    pdl[n][m] = 2.f*s - sql[n] - sql[m];
  }
  __syncthreads();
  if(t < 50){
    float pv = INFINITY; int pi = -1;
    for(int k = 0; k < 9; k++){
      float bv = -INFINITY; int bi = 1000;
      for(int m = 0; m < 50; m++){
        float v = pdl[t][m];
        bool elig = (v < pv) || (v == pv && m > pi);
        if(elig && (v > bv || (v == bv && m < bi))){ bv = v; bi = m; }
      }
      idxl[t][k] = bi; pv = bv; pi = bi;
    }
  }
  __syncthreads();
  float acc[32];
  bool act = (t < 150);
  if(act){
    int n = t / 3, jw = t % 3;
    #pragma unroll
    for(int o = 0; o < 32; o++) acc[o] = 0.f;
    for(int t3 = 0; t3 < 3; t3++){
      int kx = idxl[n][jw*3 + t3];
      for(int ii = 0; ii < 32; ii++){
        float c0 = xtl[n][ii];
        float c1 = c0 - xtl[kx][ii];
        const float* wr0 = w1l + (ii*3 + t3)*32;
        const float* wr1 = w1l + ((ii+32)*3 + t3)*32;
        #pragma unroll
        for(int o = 0; o < 32; o++) acc[o] += c0*wr0[o] + c1*wr1[o];
      }
    }
    float* out = ws + O_H1 + ((size_t)(b*4 + h)*150 + n*3 + jw)*32;
    #pragma unroll
    for(int o = 0; o < 32; o++){ acc[o] += g1bias[h*32 + o]; out[o] = acc[o]; }
  }
  __syncthreads();
  if(act){
    #pragma unroll
    for(int o = 0; o < 32; o++) w1l[t*32 + o] = acc[o];
  }
  __syncthreads();
  {
    int o = t & 31, part = t >> 5;
    float s = 0.f, sq = 0.f;
    for(int r = part; r < 150; r += 8){
      float v = w1l[r*32 + o];
      s += v; sq += v*v;
    }
    float* sp = &pdl[0][0];
    sp[part*32 + o] = s; sp[256 + part*32 + o] = sq;
    __syncthreads();
    if(t < 32){
      float S = 0.f, Q = 0.f;
      for(int p = 0; p < 8; p++){ S += sp[p*32 + t]; Q += sp[256 + p*32 + t]; }
      ws[O_P1 + b*256 + h*32 + t]       = S;
      ws[O_P1 + b*256 + 128 + h*32 + t] = Q;
    }
  }
}

// ---------------- K7: BN1(inline)+relu then conv2 (1x3) + BN2 partials ----------------
__global__ __launch_bounds__(256) void k_conv2(const float* __restrict__ g1g,
                                               const float* __restrict__ g1be,
                                               const float* __restrict__ g2w,
                                               const float* __restrict__ g2bias,
                                               float* __restrict__ ws){
  int h = blockIdx.x, b = blockIdx.y;
  __shared__ float hl[150][33];
  __shared__ float w2l[3072];
  __shared__ float rs[8][32], rq[8][32];
  __shared__ float b1s[32], b1t[32];
  int t = threadIdx.x;
  if(t < 32){
    float s = 0.f, sq = 0.f;
    for(int bb = 0; bb < 64; bb++){
      s  += ws[O_P1 + bb*256 + h*32 + t];
      sq += ws[O_P1 + bb*256 + 128 + h*32 + t];
    }
    float mean = s * (1.f/9600.f), var = sq * (1.f/9600.f) - mean*mean;
    float sc = g1g[h*32+t] * rsqrtf(var + 1e-5f);
    b1s[t] = sc; b1t[t] = g1be[h*32+t] - sc*mean;
  }
  for(int i = t; i < 3072; i += 256){
    int o = i / 96, r = i % 96, ii = r / 3, tt = r % 3;
    w2l[(ii*3 + tt)*32 + o] = g2w[(size_t)h*3072 + i];
  }
  __syncthreads();
  const float* h1p = ws + O_H1 + (size_t)(b*4 + h)*4800;
  for(int i = t; i < 4800; i += 256){
    int nj = i >> 5, ii = i & 31;
    hl[nj][ii] = fmaxf(b1s[ii]*h1p[i] + b1t[ii], 0.f);
  }
  __syncthreads();
  int o = t & 31, ng = t >> 5;
  float bias = g2bias[h*32 + o];
  float s = 0.f, sq = 0.f;
  for(int n = ng; n < 50; n += 8){
    float acc = 0.f;
    for(int t3 = 0; t3 < 3; t3++){
      const float* hr = hl[n*3 + t3];
      #pragma unroll
      for(int ii = 0; ii < 32; ii++) acc += hr[ii] * w2l[(ii*3 + t3)*32 + o];
    }
    acc += bias;
    ws[O_H2 + ((size_t)(b*4 + h)*50 + n)*32 + o] = acc;
    s += acc; sq += acc*acc;
  }
  rs[ng][o] = s; rq[ng][o] = sq; __syncthreads();
  if(t < 32){
    float S = 0.f, Q = 0.f;
    for(int g2 = 0; g2 < 8; g2++){ S += rs[g2][t]; Q += rq[g2][t]; }
    ws[O_P2 + (b*4 + h)*64 + t]      = S;
    ws[O_P2 + (b*4 + h)*64 + 32 + t] = Q;
  }
}

// ---------------- K8: BN2(inline) + tiny attention (norm folded into PV) + cat ----------------
__global__ __launch_bounds__(256) void k_attn(const float* __restrict__ g2g,
                                              const float* __restrict__ g2be,
                                              float* __restrict__ ws){
  int h = blockIdx.x, b = blockIdx.y;
  __shared__ float qtl[50][33], ktl[50][33], vtl[50][33], al[50][52];
  __shared__ float b2s[32], b2t[32];
  __shared__ float zr[50];
  int t = threadIdx.x;
  if(t < 32){
    float s = 0.f, sq = 0.f;
    for(int bb = 0; bb < 64; bb++){
      s  += ws[O_P2 + (size_t)(bb*4 + h)*64 + t];
      sq += ws[O_P2 + (size_t)(bb*4 + h)*64 + 32 + t];
    }
    float mean = s * (1.f/3200.f), var = sq * (1.f/3200.f) - mean*mean;
    float sc = g2g[h*32+t] * rsqrtf(var + 1e-5f);
    b2s[t] = sc; b2t[t] = g2be[h*32+t] - sc*mean;
  }
  size_t base = (size_t)(b*4 + h)*1600;
  for(int i = t; i < 1600; i += 256){
    int n = i >> 5, d = i & 31;
    qtl[n][d] = ws[O_QT + base + i];
    ktl[n][d] = ws[O_KT + base + i];
    vtl[n][d] = ws[O_VT + base + i];
  }
  __syncthreads();
  for(int i = t; i < 2500; i += 256){
    int n = i / 50, m = i % 50;
    float s = 0.f;
    for(int d = 0; d < 32; d++) s += qtl[n][d]*ktl[m][d];
    al[n][m] = s * 0.17677669529663687f;
  }
  __syncthreads();
  if(t < 50){
    float m = -INFINITY;
    for(int j = 0; j < 50; j++) m = fmaxf(m, al[t][j]);
    float s = 0.f;
    for(int j = 0; j < 50; j++){ float e = expf(al[t][j] - m); al[t][j] = e; s += e; }
    zr[t] = 1.f/s;
  }
  __syncthreads();
  for(int i = t; i < 1600; i += 256){
    int n = i >> 5, d = i & 31;
    float gacc = 0.f;
    for(int m = 0; m < 50; m++) gacc += al[n][m]*vtl[m][d];
    ws[O_CAT + ((size_t)b*256 + h*64 + 32 + d)*50 + n] = gacc * zr[n];
    float l = fmaxf(b2s[d]*ws[O_H2 + ((size_t)(b*4 + h)*50 + n)*32 + d] + b2t[d], 0.f);
    ws[O_CAT + ((size_t)b*256 + h*64 + d)*50 + n] = l;
  }
}

// ---------------- K9: pres2[b][c][o] = (M @ cat)[o][c] + vproj[o], o-split ----------------
__global__ __launch_bounds__(256) void k_res(float* __restrict__ ws){
  int oh = blockIdx.x & 1, b = blockIdx.x >> 1;   // 128 blocks
  __shared__ float mtl[64*68];
  __shared__ float catl[64*52];
  __shared__ float vp[64];
  int t = threadIdx.x;
  if(t < 64) vp[t] = ws[O_VPROJ + oh*64 + t];
  int og = t >> 4, cg = t & 15;
  int ob = og*4, cb = cg*4;
  float acc[4][4];
  #pragma unroll
  for(int r = 0; r < 4; r++){ acc[r][0]=0.f; acc[r][1]=0.f; acc[r][2]=0.f; acc[r][3]=0.f; }
  for(int kc = 0; kc < 4; kc++){
    int k0 = kc*64;
    __syncthreads();
    for(int i = t; i < 1024; i += 256){
      int k = i >> 4, oq = i & 15;
      float4 m = *(const float4*)&ws[O_MT + (size_t)(k0 + k)*128 + oh*64 + oq*4];
      *(float4*)&mtl[k*68 + oq*4] = m;
    }
    for(int i = t; i < 3328; i += 256){
      int k = i / 52, c = i % 52;
      catl[i] = (c < 50) ? ws[O_CAT + (size_t)b*12800 + (k0 + k)*50 + c] : 0.f;
    }
    __syncthreads();
    if(cg < 13){
      #pragma unroll 2
      for(int k = 0; k < 64; k++){
        float4 m0 = *(const float4*)&mtl[k*68 + ob];
        float4 cv = *(const float4*)&catl[k*52 + cb];
        acc[0][0] += m0.x*cv.x; acc[0][1] += m0.x*cv.y; acc[0][2] += m0.x*cv.z; acc[0][3] += m0.x*cv.w;
        acc[1][0] += m0.y*cv.x; acc[1][1] += m0.y*cv.y; acc[1][2] += m0.y*cv.z; acc[1][3] += m0.y*cv.w;
        acc[2][0] += m0.z*cv.x; acc[2][1] += m0.z*cv.y; acc[2][2] += m0.z*cv.z; acc[2][3] += m0.z*cv.w;
        acc[3][0] += m0.w*cv.x; acc[3][1] += m0.w*cv.y; acc[3][2] += m0.w*cv.z; acc[3][3] += m0.w*cv.w;
      }
    }
  }
  if(cg < 13){
    #pragma unroll
    for(int s = 0; s < 4; s++){
      int c = cb + s;
      if(c < 50){
        float4 o0 = make_float4(acc[0][s]+vp[ob+0], acc[1][s]+vp[ob+1], acc[2][s]+vp[ob+2], acc[3][s]+vp[ob+3]);
        *(float4*)&ws[O_PRES2 + (size_t)b*6400 + c*128 + oh*64 + ob] = o0;
      }
    }
  }
}

// ---------------- K10: out = pres2 @ (expE2 / Z) + proj_b  (exp-factorized) ----------------
__global__ __launch_bounds__(256) void k_out(const float* __restrict__ projb,
                                             float* __restrict__ ws,
                                             float* __restrict__ out){
  int nt = blockIdx.x, b = blockIdx.y;
  int n0 = nt*64;
  __shared__ float sl[50*64];      // [c][j] = exp(E2)
  __shared__ float p2l[50*132];
  __shared__ float pb[128];
  __shared__ float zp[4][64];
  __shared__ float zi[64];
  int t = threadIdx.x;
  for(int i = t; i < 3200; i += 256){
    int c = i >> 6, j = i & 63, n = n0 + j;
    sl[i] = (n < 4000) ? ws[O_E2 + ((size_t)b*50 + c)*4000 + n] : 0.f;
  }
  for(int i = t; i < 6400; i += 256){
    int c = i >> 7, o = i & 127;
    p2l[c*132 + o] = ws[O_PRES2 + (size_t)b*6400 + c*128 + o];
  }
  if(t < 128) pb[t] = projb[t];
  __syncthreads();
  {
    int j = t & 63, q = t >> 6;    // 4 threads per column
    float s = 0.f;
    for(int c = q; c < 50; c += 4) s += sl[c*64 + j];
    zp[q][j] = s;
  }
  __syncthreads();
  if(t < 64) zi[t] = 1.f / (zp[0][t] + zp[1][t] + zp[2][t] + zp[3][t]);
  __syncthreads();
  int og = t >> 4, jg = t & 15;
  int ob = og*8, j4 = jg*4;
  float acc[8][4];
  #pragma unroll
  for(int r = 0; r < 8; r++){ acc[r][0]=0.f; acc[r][1]=0.f; acc[r][2]=0.f; acc[r][3]=0.f; }
  #pragma unroll 2
  for(int c = 0; c < 50; c++){
    float4 sv = *(const float4*)&sl[c*64 + j4];
    float4 p0 = *(const float4*)&p2l[c*132 + ob];
    float4 p1 = *(const float4*)&p2l[c*132 + ob + 4];
    acc[0][0] += p0.x*sv.x; acc[0][1] += p0.x*sv.y; acc[0][2] += p0.x*sv.z; acc[0][3] += p0.x*sv.w;
    acc[1][0] += p0.y*sv.x; acc[1][1] += p0.y*sv.y; acc[1][2] += p0.y*sv.z; acc[1][3] += p0.y*sv.w;
    acc[2][0] += p0.z*sv.x; acc[2][1] += p0.z*sv.y; acc[2][2] += p0.z*sv.z; acc[2][3] += p0.z*sv.w;
    acc[3][0] += p0.w*sv.x; acc[3][1] += p0.w*sv.y; acc[3][2] += p0.w*sv.z; acc[3][3] += p0.w*sv.w;
    acc[4][0] += p1.x*sv.x; acc[4][1] += p1.x*sv.y; acc[4][2] += p1.x*sv.z; acc[4][3] += p1.x*sv.w;
    acc[5][0] += p1.y*sv.x; acc[5][1] += p1.y*sv.y; acc[5][2] += p1.y*sv.z; acc[5][3] += p1.y*sv.w;
    acc[6][0] += p1.z*sv.x; acc[6][1] += p1.z*sv.y; acc[6][2] += p1.z*sv.z; acc[6][3] += p1.z*sv.w;
    acc[7][0] += p1.w*sv.x; acc[7][1] += p1.w*sv.y; acc[7][2] += p1.w*sv.z; acc[7][3] += p1.w*sv.w;
  }
  int n = n0 + j4;
  if(n < 4000){
    float z0 = zi[j4+0], z1 = zi[j4+1], z2 = zi[j4+2], z3 = zi[j4+3];
    #pragma unroll
    for(int r = 0; r < 8; r++){
      float bv = pb[ob + r];
      float4 o = make_float4(acc[r][0]*z0+bv, acc[r][1]*z1+bv, acc[r][2]*z2+bv, acc[r][3]*z3+bv);
      *(float4*)&out[(size_t)(b*128 + ob + r)*4000 + n] = o;
    }
  }
}

extern "C" void kernel_launch(void* const* d_in, const int* in_sizes, int n_in,
                              void* d_out, int out_size, void* d_ws, size_t ws_size,
                              hipStream_t stream){
  (void)in_sizes; (void)n_in; (void)out_size; (void)ws_size;
  const float* x      = (const float*)d_in[0];
  const float* wg1    = (const float*)d_in[1];
  const float* bg1    = (const float*)d_in[2];
  const float* g1g    = (const float*)d_in[3];
  const float* g1b    = (const float*)d_in[4];
  const float* wg2    = (const float*)d_in[5];
  const float* bg2    = (const float*)d_in[6];
  const float* g2g    = (const float*)d_in[7];
  const float* g2b    = (const float*)d_in[8];
  const float* qkvw   = (const float*)d_in[9];
  const float* qkvb   = (const float*)d_in[10];
  const float* qkv1w  = (const float*)d_in[11];
  const float* qkv1b  = (const float*)d_in[12];
  const float* gc1w   = (const float*)d_in[13];
  const float* gc1bias= (const float*)d_in[14];
  const float* gc1g   = (const float*)d_in[15];
  const float* gc1be  = (const float*)d_in[16];
  const float* gc2w   = (const float*)d_in[17];
  const float* gc2bias= (const float*)d_in[18];
  const float* gc2g   = (const float*)d_in[19];
  const float* gc2be  = (const float*)d_in[20];
  const float* presw  = (const float*)d_in[21];
  const float* presb  = (const float*)d_in[22];
  const float* projw  = (const float*)d_in[23];
  const float* projb  = (const float*)d_in[24];
  float* ws = (float*)d_ws;
  float* out = (float*)d_out;

  k_stats<<<2112, 256, 0, stream>>>(x, projw, ws);
  k_mprep<<<130, 256, 0, stream>>>(presw, presb, g1g, g1b, g2g, g2b, ws);
  k_embed<<<1280, 256, 0, stream>>>(x, wg1, bg1, wg2, bg2, ws);
  k_qkv<<<dim3(8, 64), 256, 0, stream>>>(qkvw, qkvb, qkv1w, qkv1b, ws);
  k_knn<<<dim3(4, 64), 256, 0, stream>>>(gc1w, gc1bias, ws);
  k_conv2<<<dim3(4, 64), 256, 0, stream>>>(gc1g, gc1be, gc2w, gc2bias, ws);
  k_attn<<<dim3(4, 64), 256, 0, stream>>>(gc2g, gc2be, ws);
  k_res<<<128, 256, 0, stream>>>(ws);
  k_out<<<dim3(63, 64), 256, 0, stream>>>(projb, ws, out);
}

// Round 11
// 756.072 us; speedup vs baseline: 1.0998x; 1.0998x over previous
//
#include <hip/hip_runtime.h>
#include <cstddef>

// EfficientAttention pipeline, MI355X. fp32 throughout.
// B=64, DIM=128, N=4000, H=4, DH=32, CL=50, K=9.
// R13: revert R12 merge (falsified: union-LDS forced e2 to 2blk/CU and
// co-resident roles summed, not overlapped; 352us vs 282 sequential).
// Base = verified R11 (763.6us). Changes: (1) k_mprep/VPROJ read projw
// directly (drop PROJWT transpose + dependency), (2) k_res o-quartered to
// 256 blocks (was 128 = half the CUs).

// ---- workspace offsets (in floats) ----
constexpr size_t O_MU    = 0;                   // 8192
constexpr size_t O_RINV  = 8192;
constexpr size_t O_RATIO = 16384;
constexpr size_t O_A1    = 24576;
constexpr size_t O_B1    = 24704;
constexpr size_t O_A2    = 24832;
constexpr size_t O_B2    = 24960;
constexpr size_t O_VPROJ = 41472;               // 128
constexpr size_t O_MT    = 41600;               // 256x128 -> end 74368
constexpr size_t O_E2    = 74368;               // 64*50*4000 exp(embed2)
constexpr size_t O_UCXP  = 12874368;            // 8*64*132*56 = 3784704
constexpr size_t O_XT    = 16659072;            // 4x 409600
constexpr size_t O_QT    = 17068672;
constexpr size_t O_KT    = 17478272;
constexpr size_t O_VT    = 17887872;
constexpr size_t O_H1    = 18297472;            // 1228800
constexpr size_t O_P1    = 19526272;            // 16384
constexpr size_t O_H2    = 19542656;            // 409600
constexpr size_t O_P2    = 19952256;            // 16384
constexpr size_t O_CAT   = 19968640;            // 819200
constexpr size_t O_PRES2 = 20787840;            // 409600 -> 21197440 (84.8MB peak)

// ---------------- K1: instance-norm stats (wave-per-row) ----------------
__global__ __launch_bounds__(256) void k_stats(const float* __restrict__ x,
                                               float* __restrict__ ws){
  int w = threadIdx.x >> 6, lane = threadIdx.x & 63;
  int row = blockIdx.x*4 + w;
  const float4* xr = (const float4*)(x + (size_t)row * 4000);
  float s = 0.f, sq = 0.f;
  for(int i = lane; i < 1000; i += 64){
    float4 v = xr[i];
    s  += v.x + v.y + v.z + v.w;
    sq += v.x*v.x + v.y*v.y + v.z*v.z + v.w*v.w;
  }
  for(int off = 32; off > 0; off >>= 1){
    s  += __shfl_down(s,  off, 64);
    sq += __shfl_down(sq, off, 64);
  }
  if(lane == 0){
    float mean = s * (1.f/4000.f);
    float var  = sq * (1.f/4000.f) - mean*mean;
    ws[O_MU   + row] = mean;
    ws[O_RINV + row] = rsqrtf(var + 1e-3f);
    ws[O_RATIO+ row] = var / (var + 1e-3f);
  }
}

// ---------------- K2: M^T (0..127), VPROJ (128), BN affine prep (129) ----------------
// projw read directly: projw^T[d][o] == projw[o*128+d] (L2-resident, per-thread rows).
__global__ __launch_bounds__(256) void k_mprep(const float* __restrict__ projw,
                                               const float* __restrict__ presw,
                                               const float* __restrict__ presb,
                                               const float* __restrict__ g1g,
                                               const float* __restrict__ g1b,
                                               const float* __restrict__ g2g,
                                               const float* __restrict__ g2b,
                                               float* __restrict__ ws){
  int t = threadIdx.x;
  if(blockIdx.x < 128){
    int kk2 = blockIdx.x * 2;
    __shared__ float pwc[2][128];
    { int which = t >> 7, d = t & 127; pwc[which][d] = presw[d*256 + kk2 + which]; }
    __syncthreads();
    int which = t >> 7, o = t & 127;
    const float* pr = projw + o*128;
    float acc = 0.f;
    for(int d = 0; d < 128; d++) acc += pr[d] * pwc[which][d];
    ws[O_MT + (size_t)(kk2 + which)*128 + o] = acc;
  }else if(blockIdx.x == 128){
    if(t < 128){
      const float* pr = projw + t*128;
      float v = 0.f;
      for(int d = 0; d < 128; d++) v += pr[d] * presb[d];
      ws[O_VPROJ + t] = v;
    }
  }else{
    if(t < 128){
      float s = 0.f;
      for(int b = 0; b < 64; b++) s += ws[O_RATIO + b*128 + t];
      float var2 = s * (1.f/64.f);
      float inv2 = rsqrtf(var2 + 1e-5f);
      ws[O_A1+t] = g1g[t] * inv2;  ws[O_B1+t] = g1b[t];
      ws[O_A2+t] = g2g[t] * inv2;  ws[O_B2+t] = g2b[t];
    }
  }
}

// ---------------- K3: fused embed1 + exp + cluster GEMM partials + Z (verified) ----------------
// grid (8 ch, 64 b), 256 thr, chunk 500 = 11 subtiles of 48 (last 20). LDS ~76KB -> 2 blk/CU.
__global__ __launch_bounds__(256) void k_e1ucx(const float* __restrict__ x,
    const float* __restrict__ wg1, const float* __restrict__ bg1,
    float* __restrict__ ws){
  int ch = blockIdx.x, b = blockIdx.y;
  __shared__ float lW1[128*52];     // [c][cl], rows 50,51 zero
  __shared__ float lrv1[128*48];    // relu1 [c][n]; after E1: eU overlay [52][48]
  __shared__ float lxt [48*132];    // x^T [n][d], pad 132
  __shared__ float ca1[128], cb1[128];
  __shared__ float bg1p[56];
  int t = threadIdx.x;
  if(t < 128){
    float mu = ws[O_MU + b*128 + t], ri = ws[O_RINV + b*128 + t];
    float a1 = ws[O_A1+t]*ri;
    ca1[t] = a1; cb1[t] = ws[O_B1+t] - a1*mu;
  }
  if(t < 56) bg1p[t] = (t < 50) ? bg1[t] : 0.f;
  for(int i = t; i < 1664; i += 256){
    int cl = i >> 5, cq = i & 31;
    float4 w = (cl < 50) ? *(const float4*)&wg1[cl*128 + cq*4] : make_float4(0.f,0.f,0.f,0.f);
    int c0 = cq*4;
    lW1[(c0+0)*52+cl] = w.x; lW1[(c0+1)*52+cl] = w.y;
    lW1[(c0+2)*52+cl] = w.z; lW1[(c0+3)*52+cl] = w.w;
  }
  // UCX map: 224 active threads, tile 4d x 8c
  int dg = t & 31, cg = t >> 5;
  float ua[4][8];
  #pragma unroll
  for(int r = 0; r < 4; r++)
    #pragma unroll
    for(int i = 0; i < 8; i++) ua[r][i] = 0.f;
  float zacc = 0.f;
  // E1 map: tile 4cl x 4n
  int ig = t >> 4, jg = t & 15;
  int clb = ig*4, j4 = jg*4;
  // stage mapping: 6 float4 per thread
  int sc[6], sj[6];
  float4 pf[6];
  #pragma unroll
  for(int j = 0; j < 6; j++){ int i = t + 256*j; sc[j] = i/12; sj[j] = (i%12)*4; }
  #pragma unroll
  for(int j = 0; j < 6; j++)
    pf[j] = *(const float4*)&x[(size_t)(b*128 + sc[j])*4000 + ch*500 + sj[j]];

  for(int st = 0; st < 11; st++){
    int lim = (st == 10) ? 20 : 48;
    __syncthreads();
    // stage from regs: lxt[n][d] raw (+zeros pad), lrv1 = relu(affine)
    #pragma unroll
    for(int j = 0; j < 6; j++){
      int c = sc[j], jj = sj[j];
      float4 xv = (jj < lim) ? pf[j] : make_float4(0.f,0.f,0.f,0.f);
      lxt[(jj+0)*132 + c] = xv.x; lxt[(jj+1)*132 + c] = xv.y;
      lxt[(jj+2)*132 + c] = xv.z; lxt[(jj+3)*132 + c] = xv.w;
      float a1 = ca1[c], b1v = cb1[c];
      float4 r1;
      r1.x = fmaxf(a1*xv.x + b1v, 0.f); r1.y = fmaxf(a1*xv.y + b1v, 0.f);
      r1.z = fmaxf(a1*xv.z + b1v, 0.f); r1.w = fmaxf(a1*xv.w + b1v, 0.f);
      *(float4*)&lrv1[c*48 + jj] = r1;
    }
    __syncthreads();
    // prefetch next subtile (flies during E1/exp/UCX)
    if(st < 10){
      int lim2 = (st == 9) ? 20 : 48;
      int nb2 = ch*500 + (st+1)*48;
      #pragma unroll
      for(int j = 0; j < 6; j++)
        pf[j] = (sj[j] < lim2) ? *(const float4*)&x[(size_t)(b*128 + sc[j])*4000 + nb2 + sj[j]]
                               : make_float4(0.f,0.f,0.f,0.f);
    }
    // E1 GEMM: 52 rows x 48 cols
    float e[4][4];
    if(ig < 13 && jg < 12){
      #pragma unroll
      for(int r = 0; r < 4; r++){ e[r][0]=0.f; e[r][1]=0.f; e[r][2]=0.f; e[r][3]=0.f; }
      #pragma unroll 4
      for(int c = 0; c < 128; c++){
        float4 w = *(const float4*)&lW1[c*52 + clb];
        float4 v = *(const float4*)&lrv1[c*48 + j4];
        e[0][0] += w.x*v.x; e[0][1] += w.x*v.y; e[0][2] += w.x*v.z; e[0][3] += w.x*v.w;
        e[1][0] += w.y*v.x; e[1][1] += w.y*v.y; e[1][2] += w.y*v.z; e[1][3] += w.y*v.w;
        e[2][0] += w.z*v.x; e[2][1] += w.z*v.y; e[2][2] += w.z*v.z; e[2][3] += w.z*v.w;
        e[3][0] += w.w*v.x; e[3][1] += w.w*v.y; e[3][2] += w.w*v.z; e[3][3] += w.w*v.w;
      }
    }
    __syncthreads();                 // E1 reads of lrv1 done -> overlay eU
    if(ig < 13 && jg < 12){
      bool live = (j4 < lim);
      #pragma unroll
      for(int r = 0; r < 4; r++){
        float bias = bg1p[clb + r];
        float4 u = make_float4(0.f,0.f,0.f,0.f);
        if(live){
          u.x = expf(e[r][0] + bias); u.y = expf(e[r][1] + bias);
          u.z = expf(e[r][2] + bias); u.w = expf(e[r][3] + bias);
        }
        *(float4*)&lrv1[(clb + r)*48 + j4] = u;
      }
    }
    __syncthreads();
    // UCX accumulate: ua[d][c] += x[d][n]*eU[c][n]
    if(t < 224){
      int d4 = dg*4, c8 = cg*8;
      for(int n4 = 0; n4 < 12; n4++){
        int n0 = n4*4;
        float4 uv[8];
        #pragma unroll
        for(int i = 0; i < 8; i++) uv[i] = *(const float4*)&lrv1[(c8 + i)*48 + n0];
        {
          float4 xq = *(const float4*)&lxt[(n0+0)*132 + d4];
          #pragma unroll
          for(int i = 0; i < 8; i++){
            float u = uv[i].x;
            ua[0][i] += xq.x*u; ua[1][i] += xq.y*u; ua[2][i] += xq.z*u; ua[3][i] += xq.w*u;
          }
        }
        {
          float4 xq = *(const float4*)&lxt[(n0+1)*132 + d4];
          #pragma unroll
          for(int i = 0; i < 8; i++){
            float u = uv[i].y;
            ua[0][i] += xq.x*u; ua[1][i] += xq.y*u; ua[2][i] += xq.z*u; ua[3][i] += xq.w*u;
          }
        }
        {
          float4 xq = *(const float4*)&lxt[(n0+2)*132 + d4];
          #pragma unroll
          for(int i = 0; i < 8; i++){
            float u = uv[i].z;
            ua[0][i] += xq.x*u; ua[1][i] += xq.y*u; ua[2][i] += xq.z*u; ua[3][i] += xq.w*u;
          }
        }
        {
          float4 xq = *(const float4*)&lxt[(n0+3)*132 + d4];
          #pragma unroll
          for(int i = 0; i < 8; i++){
            float u = uv[i].w;
            ua[0][i] += xq.x*u; ua[1][i] += xq.y*u; ua[2][i] += xq.z*u; ua[3][i] += xq.w*u;
          }
        }
      }
    }
    // Z: row-sum of masked eU
    if(t < 52){
      float s = 0.f;
      #pragma unroll
      for(int k = 0; k < 12; k++){
        float4 u = *(const float4*)&lrv1[t*48 + k*4];
        s += u.x + u.y + u.z + u.w;
      }
      zacc += s;
    }
  }
  // write partials [ch][b][132][56]: rows 0..127 = UCX, row 128 = Z
  if(t < 224){
    int d4 = dg*4, c8 = cg*8;
    #pragma unroll
    for(int r = 0; r < 4; r++){
      size_t base = O_UCXP + ((size_t)(ch*64 + b)*132 + d4 + r)*56 + c8;
      *(float4*)&ws[base]     = make_float4(ua[r][0], ua[r][1], ua[r][2], ua[r][3]);
      *(float4*)&ws[base + 4] = make_float4(ua[r][4], ua[r][5], ua[r][6], ua[r][7]);
    }
  }
  if(t < 52) ws[O_UCXP + ((size_t)(ch*64 + b)*132 + 128)*56 + t] = zacc;
}

// ---------------- K4: embed2 -> exp(logits) in O_E2 ----------------
// grid (12 ch, 64 b), 256 thr, chunk 336. LDS ~51KB -> 3 blk/CU.
__global__ __launch_bounds__(256, 3) void k_e2(const float* __restrict__ x,
    const float* __restrict__ wg2, const float* __restrict__ bg2,
    float* __restrict__ ws){
  int ch = blockIdx.x, b = blockIdx.y;
  __shared__ float lW2[128*52];
  __shared__ float lrv2[128*48];
  __shared__ float ca2[128], cb2[128];
  __shared__ float bg2p[56];
  int t = threadIdx.x;
  if(t < 128){
    float mu = ws[O_MU + b*128 + t], ri = ws[O_RINV + b*128 + t];
    float a2 = ws[O_A2+t]*ri;
    ca2[t] = a2; cb2[t] = ws[O_B2+t] - a2*mu;
  }
  if(t >= 192 && t < 248){ int q = t - 192; bg2p[q] = (q < 50) ? bg2[q] : 0.f; }
  for(int i = t; i < 1664; i += 256){
    int cl = i >> 5, cq = i & 31;
    float4 w = (cl < 50) ? *(const float4*)&wg2[cl*128 + cq*4] : make_float4(0.f,0.f,0.f,0.f);
    int c0 = cq*4;
    lW2[(c0+0)*52+cl] = w.x; lW2[(c0+1)*52+cl] = w.y;
    lW2[(c0+2)*52+cl] = w.z; lW2[(c0+3)*52+cl] = w.w;
  }
  int ig = t >> 4, jg = t & 15;
  int clb = ig*4, j4 = jg*4;
  int sc[6], sj[6];
  float4 pf[6];
  #pragma unroll
  for(int j = 0; j < 6; j++){ int i = t + 256*j; sc[j] = i/12; sj[j] = (i%12)*4; }
  #pragma unroll
  for(int j = 0; j < 6; j++)
    pf[j] = *(const float4*)&x[(size_t)(b*128 + sc[j])*4000 + ch*336 + sj[j]];

  for(int st = 0; st < 7; st++){
    int nb = ch*336 + st*48;
    int lim = 4000 - nb; if(lim > 48) lim = 48;
    __syncthreads();
    #pragma unroll
    for(int j = 0; j < 6; j++){
      int c = sc[j], jj = sj[j];
      float4 xv = (jj < lim) ? pf[j] : make_float4(0.f,0.f,0.f,0.f);
      float a2 = ca2[c], b2v = cb2[c];
      float4 r2;
      r2.x = fmaxf(a2*xv.x + b2v, 0.f); r2.y = fmaxf(a2*xv.y + b2v, 0.f);
      r2.z = fmaxf(a2*xv.z + b2v, 0.f); r2.w = fmaxf(a2*xv.w + b2v, 0.f);
      *(float4*)&lrv2[c*48 + jj] = r2;
    }
    __syncthreads();
    if(st < 6){
      int nb2 = nb + 48;
      int lim2 = 4000 - nb2; if(lim2 > 48) lim2 = 48;
      #pragma unroll
      for(int j = 0; j < 6; j++)
        pf[j] = (sj[j] < lim2) ? *(const float4*)&x[(size_t)(b*128 + sc[j])*4000 + nb2 + sj[j]]
                               : make_float4(0.f,0.f,0.f,0.f);
    }
    if(ig < 13 && jg < 12){
      float e[4][4];
      #pragma unroll
      for(int r = 0; r < 4; r++){ e[r][0]=0.f; e[r][1]=0.f; e[r][2]=0.f; e[r][3]=0.f; }
      #pragma unroll 4
      for(int c = 0; c < 128; c++){
        float4 w = *(const float4*)&lW2[c*52 + clb];
        float4 v = *(const float4*)&lrv2[c*48 + j4];
        e[0][0] += w.x*v.x; e[0][1] += w.x*v.y; e[0][2] += w.x*v.z; e[0][3] += w.x*v.w;
        e[1][0] += w.y*v.x; e[1][1] += w.y*v.y; e[1][2] += w.y*v.z; e[1][3] += w.y*v.w;
        e[2][0] += w.z*v.x; e[2][1] += w.z*v.y; e[2][2] += w.z*v.z; e[2][3] += w.z*v.w;
        e[3][0] += w.w*v.x; e[3][1] += w.w*v.y; e[3][2] += w.w*v.z; e[3][3] += w.w*v.w;
      }
      if(j4 < lim){
        #pragma unroll
        for(int r = 0; r < 4; r++){
          int cl = clb + r;
          if(cl < 50){
            float bias = bg2p[cl];
            float4 o = make_float4(expf(e[r][0]+bias), expf(e[r][1]+bias),
                                   expf(e[r][2]+bias), expf(e[r][3]+bias));
            *(float4*)&ws[O_E2 + ((size_t)b*50 + cl)*4000 + nb + j4] = o;
          }
        }
      }
    }
  }
}

// ---------------- K5: qkv + qkv1 projections, cluster_x reduced on load (8 chunks) ----------------
__global__ __launch_bounds__(256) void k_qkv(const float* __restrict__ qw,
                                             const float* __restrict__ qb,
                                             const float* __restrict__ q1w,
                                             const float* __restrict__ q1b,
                                             float* __restrict__ ws){
  int rt = blockIdx.x, b = blockIdx.y;        // 8 row-tiles of 64
  __shared__ float wl[64*130];                // [rl][k] pad 130
  __shared__ float cxl[128*52];               // [k][c]
  __shared__ float zi[52];
  int t = threadIdx.x;
  if(t < 52){
    float s = 0.f;
    if(t < 50){
      #pragma unroll
      for(int ch = 0; ch < 8; ch++)
        s += ws[O_UCXP + ((size_t)(ch*64 + b)*132 + 128)*56 + t];
      zi[t] = 1.f / s;
    }else zi[t] = 0.f;
  }
  for(int i = t; i < 2048; i += 256){
    int rl = i >> 5, kq = i & 31, row = rt*64 + rl;
    float4 w = (row < 128) ? *(const float4*)&qw[row*128 + kq*4]
                           : *(const float4*)&q1w[(row-128)*128 + kq*4];
    int k0 = kq*4;
    wl[rl*130 + k0+0] = w.x; wl[rl*130 + k0+1] = w.y;
    wl[rl*130 + k0+2] = w.z; wl[rl*130 + k0+3] = w.w;
  }
  __syncthreads();
  for(int i = t; i < 6656; i += 256){
    int k = i / 52, c = i % 52;
    float s = 0.f;
    size_t base = O_UCXP + ((size_t)b*132 + k)*56 + c;
    #pragma unroll
    for(int ch = 0; ch < 8; ch++) s += ws[base + (size_t)ch*473088];
    cxl[i] = s * zi[c];
  }
  __syncthreads();
  int ig = t & 15, cg = t >> 4;
  float acc[4][4];
  #pragma unroll
  for(int r = 0; r < 4; r++){ acc[r][0]=0.f; acc[r][1]=0.f; acc[r][2]=0.f; acc[r][3]=0.f; }
  if(cg < 13){
    int rb = ig*4, cb = cg*4;
    #pragma unroll 4
    for(int k = 0; k < 128; k++){
      float4 cv = *(const float4*)&cxl[k*52 + cb];
      float w0 = wl[(rb+0)*130 + k], w1 = wl[(rb+1)*130 + k];
      float w2 = wl[(rb+2)*130 + k], w3 = wl[(rb+3)*130 + k];
      acc[0][0] += w0*cv.x; acc[0][1] += w0*cv.y; acc[0][2] += w0*cv.z; acc[0][3] += w0*cv.w;
      acc[1][0] += w1*cv.x; acc[1][1] += w1*cv.y; acc[1][2] += w1*cv.z; acc[1][3] += w1*cv.w;
      acc[2][0] += w2*cv.x; acc[2][1] += w2*cv.y; acc[2][2] += w2*cv.z; acc[2][3] += w2*cv.w;
      acc[3][0] += w3*cv.x; acc[3][1] += w3*cv.y; acc[3][2] += w3*cv.z; acc[3][3] += w3*cv.w;
    }
    #pragma unroll
    for(int r = 0; r < 4; r++){
      int row = rt*64 + ig*4 + r;
      size_t base; float bias;
      if(row < 128){
        int h = row >> 5;
        bias = qb[row];
        base = O_XT + (size_t)(b*4 + h)*1600 + (row & 31);
      }else{
        int r2 = row - 128, h = r2/96, j = r2%96, kind = j >> 5, dd = j & 31;
        bias = q1b[r2];
        base = (kind==0 ? O_QT : kind==1 ? O_KT : O_VT) + (size_t)(b*4 + h)*1600 + dd;
      }
      #pragma unroll
      for(int s = 0; s < 4; s++){
        int c = cg*4 + s;
        if(c < 50) ws[base + (size_t)c*32] = acc[r][s] + bias;
      }
    }
  }
}

// ---------------- K6: knn (top-9) + edge + conv1 + BN1 partials ----------------
__global__ __launch_bounds__(256) void k_knn(const float* __restrict__ g1w,
                                             const float* __restrict__ g1bias,
                                             float* __restrict__ ws){
  int h = blockIdx.x, b = blockIdx.y;
  __shared__ float xtl[50][33];
  __shared__ float pdl[50][52];
  __shared__ float sql[50];
  __shared__ int   idxl[50][9];
  __shared__ float w1l[6144];                 // weights; reused as h1 stash for BN1
  int t = threadIdx.x;
  const float* xtg = ws + O_XT + (size_t)(b*4 + h)*1600;
  for(int i = t; i < 1600; i += 256) xtl[i >> 5][i & 31] = xtg[i];
  for(int i = t; i < 6144; i += 256){
    int o = i / 192, r = i % 192, ii = r / 3, tt = r % 3;
    w1l[(ii*3 + tt)*32 + o] = g1w[(size_t)h*6144 + i];
  }
  __syncthreads();
  if(t < 50){
    float s = 0.f;
    for(int d = 0; d < 32; d++){ float v = xtl[t][d]; s += v*v; }
    sql[t] = s;
  }
  __syncthreads();
  for(int i = t; i < 2500; i += 256){
    int n = i / 50, m = i % 50;
    float s = 0.f;
    for(int d = 0; d < 32; d++) s += xtl[n][d]*xtl[m][d];
    pdl[n][m] = 2.f*s - sql[n] - sql[m];
  }
  __syncthreads();
  if(t < 50){
    float pv = INFINITY; int pi = -1;
    for(int k = 0; k < 9; k++){
      float bv = -INFINITY; int bi = 1000;
      for(int m = 0; m < 50; m++){
        float v = pdl[t][m];
        bool elig = (v < pv) || (v == pv && m > pi);
        if(elig && (v > bv || (v == bv && m < bi))){ bv = v; bi = m; }
      }
      idxl[t][k] = bi; pv = bv; pi = bi;
    }
  }
  __syncthreads();
  float acc[32];
  bool act = (t < 150);
  if(act){
    int n = t / 3, jw = t % 3;
    #pragma unroll
    for(int o = 0; o < 32; o++) acc[o] = 0.f;
    for(int t3 = 0; t3 < 3; t3++){
      int kx = idxl[n][jw*3 + t3];
      for(int ii = 0; ii < 32; ii++){
        float c0 = xtl[n][ii];
        float c1 = c0 - xtl[kx][ii];
        const float* wr0 = w1l + (ii*3 + t3)*32;
        const float* wr1 = w1l + ((ii+32)*3 + t3)*32;
        #pragma unroll
        for(int o = 0; o < 32; o++) acc[o] += c0*wr0[o] + c1*wr1[o];
      }
    }
    float* out = ws + O_H1 + ((size_t)(b*4 + h)*150 + n*3 + jw)*32;
    #pragma unroll
    for(int o = 0; o < 32; o++){ acc[o] += g1bias[h*32 + o]; out[o] = acc[o]; }
  }
  __syncthreads();
  if(act){
    #pragma unroll
    for(int o = 0; o < 32; o++) w1l[t*32 + o] = acc[o];
  }
  __syncthreads();
  {
    int o = t & 31, part = t >> 5;
    float s = 0.f, sq = 0.f;
    for(int r = part; r < 150; r += 8){
      float v = w1l[r*32 + o];
      s += v; sq += v*v;
    }
    float* sp = &pdl[0][0];
    sp[part*32 + o] = s; sp[256 + part*32 + o] = sq;
    __syncthreads();
    if(t < 32){
      float S = 0.f, Q = 0.f;
      for(int p = 0; p < 8; p++){ S += sp[p*32 + t]; Q += sp[256 + p*32 + t]; }
      ws[O_P1 + b*256 + h*32 + t]       = S;
      ws[O_P1 + b*256 + 128 + h*32 + t] = Q;
    }
  }
}

// ---------------- K7: BN1(inline)+relu then conv2 (1x3) + BN2 partials ----------------
__global__ __launch_bounds__(256) void k_conv2(const float* __restrict__ g1g,
                                               const float* __restrict__ g1be,
                                               const float* __restrict__ g2w,
                                               const float* __restrict__ g2bias,
                                               float* __restrict__ ws){
  int h = blockIdx.x, b = blockIdx.y;
  __shared__ float hl[150][33];
  __shared__ float w2l[3072];
  __shared__ float rs[8][32], rq[8][32];
  __shared__ float b1s[32], b1t[32];
  int t = threadIdx.x;
  if(t < 32){
    float s = 0.f, sq = 0.f;
    for(int bb = 0; bb < 64; bb++){
      s  += ws[O_P1 + bb*256 + h*32 + t];
      sq += ws[O_P1 + bb*256 + 128 + h*32 + t];
    }
    float mean = s * (1.f/9600.f), var = sq * (1.f/9600.f) - mean*mean;
    float sc = g1g[h*32+t] * rsqrtf(var + 1e-5f);
    b1s[t] = sc; b1t[t] = g1be[h*32+t] - sc*mean;
  }
  for(int i = t; i < 3072; i += 256){
    int o = i / 96, r = i % 96, ii = r / 3, tt = r % 3;
    w2l[(ii*3 + tt)*32 + o] = g2w[(size_t)h*3072 + i];
  }
  __syncthreads();
  const float* h1p = ws + O_H1 + (size_t)(b*4 + h)*4800;
  for(int i = t; i < 4800; i += 256){
    int nj = i >> 5, ii = i & 31;
    hl[nj][ii] = fmaxf(b1s[ii]*h1p[i] + b1t[ii], 0.f);
  }
  __syncthreads();
  int o = t & 31, ng = t >> 5;
  float bias = g2bias[h*32 + o];
  float s = 0.f, sq = 0.f;
  for(int n = ng; n < 50; n += 8){
    float acc = 0.f;
    for(int t3 = 0; t3 < 3; t3++){
      const float* hr = hl[n*3 + t3];
      #pragma unroll
      for(int ii = 0; ii < 32; ii++) acc += hr[ii] * w2l[(ii*3 + t3)*32 + o];
    }
    acc += bias;
    ws[O_H2 + ((size_t)(b*4 + h)*50 + n)*32 + o] = acc;
    s += acc; sq += acc*acc;
  }
  rs[ng][o] = s; rq[ng][o] = sq; __syncthreads();
  if(t < 32){
    float S = 0.f, Q = 0.f;
    for(int g2 = 0; g2 < 8; g2++){ S += rs[g2][t]; Q += rq[g2][t]; }
    ws[O_P2 + (b*4 + h)*64 + t]      = S;
    ws[O_P2 + (b*4 + h)*64 + 32 + t] = Q;
  }
}

// ---------------- K8: BN2(inline) + tiny attention (norm folded into PV) + cat ----------------
__global__ __launch_bounds__(256) void k_attn(const float* __restrict__ g2g,
                                              const float* __restrict__ g2be,
                                              float* __restrict__ ws){
  int h = blockIdx.x, b = blockIdx.y;
  __shared__ float qtl[50][33], ktl[50][33], vtl[50][33], al[50][52];
  __shared__ float b2s[32], b2t[32];
  __shared__ float zr[50];
  int t = threadIdx.x;
  if(t < 32){
    float s = 0.f, sq = 0.f;
    for(int bb = 0; bb < 64; bb++){
      s  += ws[O_P2 + (size_t)(bb*4 + h)*64 + t];
      sq += ws[O_P2 + (size_t)(bb*4 + h)*64 + 32 + t];
    }
    float mean = s * (1.f/3200.f), var = sq * (1.f/3200.f) - mean*mean;
    float sc = g2g[h*32+t] * rsqrtf(var + 1e-5f);
    b2s[t] = sc; b2t[t] = g2be[h*32+t] - sc*mean;
  }
  size_t base = (size_t)(b*4 + h)*1600;
  for(int i = t; i < 1600; i += 256){
    int n = i >> 5, d = i & 31;
    qtl[n][d] = ws[O_QT + base + i];
    ktl[n][d] = ws[O_KT + base + i];
    vtl[n][d] = ws[O_VT + base + i];
  }
  __syncthreads();
  for(int i = t; i < 2500; i += 256){
    int n = i / 50, m = i % 50;
    float s = 0.f;
    for(int d = 0; d < 32; d++) s += qtl[n][d]*ktl[m][d];
    al[n][m] = s * 0.17677669529663687f;
  }
  __syncthreads();
  if(t < 50){
    float m = -INFINITY;
    for(int j = 0; j < 50; j++) m = fmaxf(m, al[t][j]);
    float s = 0.f;
    for(int j = 0; j < 50; j++){ float e = expf(al[t][j] - m); al[t][j] = e; s += e; }
    zr[t] = 1.f/s;
  }
  __syncthreads();
  for(int i = t; i < 1600; i += 256){
    int n = i >> 5, d = i & 31;
    float gacc = 0.f;
    for(int m = 0; m < 50; m++) gacc += al[n][m]*vtl[m][d];
    ws[O_CAT + ((size_t)b*256 + h*64 + 32 + d)*50 + n] = gacc * zr[n];
    float l = fmaxf(b2s[d]*ws[O_H2 + ((size_t)(b*4 + h)*50 + n)*32 + d] + b2t[d], 0.f);
    ws[O_CAT + ((size_t)b*256 + h*64 + d)*50 + n] = l;
  }
}

// ---------------- K9: pres2[b][c][o] = (M @ cat)[o][c] + vproj[o], o-quartered ----------------
__global__ __launch_bounds__(256) void k_res(float* __restrict__ ws){
  int oq = blockIdx.x & 3, b = blockIdx.x >> 2;   // 256 blocks
  __shared__ float mtl[64*36];     // [k][o-quarter 32] pad 36
  __shared__ float catl[64*52];    // [k][c]
  __shared__ float vp[32];
  int t = threadIdx.x;
  if(t < 32) vp[t] = ws[O_VPROJ + oq*32 + t];
  int og = t >> 4, cg = t & 15;    // o = og*2 (32 o), c = cg*4 (cg<13)
  int ob = og*2, cb = cg*4;
  float acc[2][4];
  acc[0][0]=0.f; acc[0][1]=0.f; acc[0][2]=0.f; acc[0][3]=0.f;
  acc[1][0]=0.f; acc[1][1]=0.f; acc[1][2]=0.f; acc[1][3]=0.f;
  for(int kc = 0; kc < 4; kc++){
    int k0 = kc*64;
    __syncthreads();
    for(int i = t; i < 512; i += 256){
      int k = i >> 3, o8 = (i & 7)*4;
      float4 m = *(const float4*)&ws[O_MT + (size_t)(k0 + k)*128 + oq*32 + o8];
      *(float4*)&mtl[k*36 + o8] = m;
    }
    for(int i = t; i < 3328; i += 256){
      int k = i / 52, c = i % 52;
      catl[i] = (c < 50) ? ws[O_CAT + (size_t)b*12800 + (k0 + k)*50 + c] : 0.f;
    }
    __syncthreads();
    if(cg < 13){
      #pragma unroll 4
      for(int k = 0; k < 64; k++){
        float2 m0 = *(const float2*)&mtl[k*36 + ob];
        float4 cv = *(const float4*)&catl[k*52 + cb];
        acc[0][0] += m0.x*cv.x; acc[0][1] += m0.x*cv.y; acc[0][2] += m0.x*cv.z; acc[0][3] += m0.x*cv.w;
        acc[1][0] += m0.y*cv.x; acc[1][1] += m0.y*cv.y; acc[1][2] += m0.y*cv.z; acc[1][3] += m0.y*cv.w;
      }
    }
  }
  if(cg < 13){
    #pragma unroll
    for(int s = 0; s < 4; s++){
      int c = cb + s;
      if(c < 50){
        float2 o0 = make_float2(acc[0][s]+vp[ob+0], acc[1][s]+vp[ob+1]);
        *(float2*)&ws[O_PRES2 + (size_t)b*6400 + c*128 + oq*32 + ob] = o0;
      }
    }
  }
}

// ---------------- K10: out = pres2 @ (expE2 / Z) + proj_b  (exp-factorized) ----------------
__global__ __launch_bounds__(256) void k_out(const float* __restrict__ projb,
                                             float* __restrict__ ws,
                                             float* __restrict__ out){
  int nt = blockIdx.x, b = blockIdx.y;
  int n0 = nt*64;
  __shared__ float sl[50*64];      // [c][j] = exp(E2)
  __shared__ float p2l[50*132];
  __shared__ float pb[128];
  __shared__ float zp[4][64];
  __shared__ float zi[64];
  int t = threadIdx.x;
  for(int i = t; i < 3200; i += 256){
    int c = i >> 6, j = i & 63, n = n0 + j;
    sl[i] = (n < 4000) ? ws[O_E2 + ((size_t)b*50 + c)*4000 + n] : 0.f;
  }
  for(int i = t; i < 6400; i += 256){
    int c = i >> 7, o = i & 127;
    p2l[c*132 + o] = ws[O_PRES2 + (size_t)b*6400 + c*128 + o];
  }
  if(t < 128) pb[t] = projb[t];
  __syncthreads();
  {
    int j = t & 63, q = t >> 6;    // 4 threads per column
    float s = 0.f;
    for(int c = q; c < 50; c += 4) s += sl[c*64 + j];
    zp[q][j] = s;
  }
  __syncthreads();
  if(t < 64) zi[t] = 1.f / (zp[0][t] + zp[1][t] + zp[2][t] + zp[3][t]);
  __syncthreads();
  int og = t >> 4, jg = t & 15;
  int ob = og*8, j4 = jg*4;
  float acc[8][4];
  #pragma unroll
  for(int r = 0; r < 8; r++){ acc[r][0]=0.f; acc[r][1]=0.f; acc[r][2]=0.f; acc[r][3]=0.f; }
  #pragma unroll 2
  for(int c = 0; c < 50; c++){
    float4 sv = *(const float4*)&sl[c*64 + j4];
    float4 p0 = *(const float4*)&p2l[c*132 + ob];
    float4 p1 = *(const float4*)&p2l[c*132 + ob + 4];
    acc[0][0] += p0.x*sv.x; acc[0][1] += p0.x*sv.y; acc[0][2] += p0.x*sv.z; acc[0][3] += p0.x*sv.w;
    acc[1][0] += p0.y*sv.x; acc[1][1] += p0.y*sv.y; acc[1][2] += p0.y*sv.z; acc[1][3] += p0.y*sv.w;
    acc[2][0] += p0.z*sv.x; acc[2][1] += p0.z*sv.y; acc[2][2] += p0.z*sv.z; acc[2][3] += p0.z*sv.w;
    acc[3][0] += p0.w*sv.x; acc[3][1] += p0.w*sv.y; acc[3][2] += p0.w*sv.z; acc[3][3] += p0.w*sv.w;
    acc[4][0] += p1.x*sv.x; acc[4][1] += p1.x*sv.y; acc[4][2] += p1.x*sv.z; acc[4][3] += p1.x*sv.w;
    acc[5][0] += p1.y*sv.x; acc[5][1] += p1.y*sv.y; acc[5][2] += p1.y*sv.z; acc[5][3] += p1.y*sv.w;
    acc[6][0] += p1.z*sv.x; acc[6][1] += p1.z*sv.y; acc[6][2] += p1.z*sv.z; acc[6][3] += p1.z*sv.w;
    acc[7][0] += p1.w*sv.x; acc[7][1] += p1.w*sv.y; acc[7][2] += p1.w*sv.z; acc[7][3] += p1.w*sv.w;
  }
  int n = n0 + j4;
  if(n < 4000){
    float z0 = zi[j4+0], z1 = zi[j4+1], z2 = zi[j4+2], z3 = zi[j4+3];
    #pragma unroll
    for(int r = 0; r < 8; r++){
      float bv = pb[ob + r];
      float4 o = make_float4(acc[r][0]*z0+bv, acc[r][1]*z1+bv, acc[r][2]*z2+bv, acc[r][3]*z3+bv);
      *(float4*)&out[(size_t)(b*128 + ob + r)*4000 + n] = o;
    }
  }
}

extern "C" void kernel_launch(void* const* d_in, const int* in_sizes, int n_in,
                              void* d_out, int out_size, void* d_ws, size_t ws_size,
                              hipStream_t stream){
  (void)in_sizes; (void)n_in; (void)out_size; (void)ws_size;
  const float* x      = (const float*)d_in[0];
  const float* wg1    = (const float*)d_in[1];
  const float* bg1    = (const float*)d_in[2];
  const float* g1g    = (const float*)d_in[3];
  const float* g1b    = (const float*)d_in[4];
  const float* wg2    = (const float*)d_in[5];
  const float* bg2    = (const float*)d_in[6];
  const float* g2g    = (const float*)d_in[7];
  const float* g2b    = (const float*)d_in[8];
  const float* qkvw   = (const float*)d_in[9];
  const float* qkvb   = (const float*)d_in[10];
  const float* qkv1w  = (const float*)d_in[11];
  const float* qkv1b  = (const float*)d_in[12];
  const float* gc1w   = (const float*)d_in[13];
  const float* gc1bias= (const float*)d_in[14];
  const float* gc1g   = (const float*)d_in[15];
  const float* gc1be  = (const float*)d_in[16];
  const float* gc2w   = (const float*)d_in[17];
  const float* gc2bias= (const float*)d_in[18];
  const float* gc2g   = (const float*)d_in[19];
  const float* gc2be  = (const float*)d_in[20];
  const float* presw  = (const float*)d_in[21];
  const float* presb  = (const float*)d_in[22];
  const float* projw  = (const float*)d_in[23];
  const float* projb  = (const float*)d_in[24];
  float* ws = (float*)d_ws;
  float* out = (float*)d_out;

  k_stats<<<2048, 256, 0, stream>>>(x, ws);
  k_mprep<<<130, 256, 0, stream>>>(projw, presw, presb, g1g, g1b, g2g, g2b, ws);
  k_e1ucx<<<dim3(8, 64), 256, 0, stream>>>(x, wg1, bg1, ws);
  k_e2<<<dim3(12, 64), 256, 0, stream>>>(x, wg2, bg2, ws);
  k_qkv<<<dim3(8, 64), 256, 0, stream>>>(qkvw, qkvb, qkv1w, qkv1b, ws);
  k_knn<<<dim3(4, 64), 256, 0, stream>>>(gc1w, gc1bias, ws);
  k_conv2<<<dim3(4, 64), 256, 0, stream>>>(gc1g, gc1be, gc2w, gc2bias, ws);
  k_attn<<<dim3(4, 64), 256, 0, stream>>>(gc2g, gc2be, ws);
  k_res<<<256, 256, 0, stream>>>(ws);
  k_out<<<dim3(63, 64), 256, 0, stream>>>(projb, ws, out);
}